// Round 11
// baseline (291.714 us; speedup 1.0000x reference)
//
#include <hip/hip_runtime.h>
#include <math.h>

#define S 2048
#define B 16
#define H 512
#define L 4096
#define SMAX 16
#define LAB 256
#define V 32000
#define NCH 250          // V / 128 vocab chunks
#define LOG2E 1.44269504f

typedef __attribute__((ext_vector_type(8))) short short8;
typedef __attribute__((ext_vector_type(4))) float float4v;

__device__ inline ushort f2bf(float x) {
  union { float f; unsigned u; } c; c.f = x;
  unsigned r = c.u + 0x7fffu + ((c.u >> 16) & 1u);
  return (ushort)(r >> 16);
}
__device__ inline float bf2f(ushort h) {
  union { unsigned u; float f; } c; c.u = ((unsigned)h) << 16;
  return c.f;
}

// ---------------------------------------------------------------- kernel P
// Fused prep: blocks [0,2048) span gather; [2048,2144) W1 tcast;
// [2144,2160) W2 tcast; [2160,4160) Wo frag-major tcast.
// R11: Wo writes COALESCED. Old loop wrote 512 scattered 16B stores/tile
// (consecutive threads ~1KB apart -> ~4x write amplification on 16.4MB).
// The 64x64 tile is exactly 8 complete 1KB frags (4 nt x 2 k4); each
// 64-thread group now writes one frag's 64 consecutive 16B slots.
__global__ __launch_bounds__(256) void prep_kernel(
    const float* __restrict__ hidden, const int* __restrict__ begins,
    const int* __restrict__ ends, const int* __restrict__ bids,
    ushort* __restrict__ spanb, const float* __restrict__ W1,
    ushort* __restrict__ W1b, const float* __restrict__ W2,
    ushort* __restrict__ W2b, const float* __restrict__ Wo,
    ushort* __restrict__ Wob) {
  __shared__ ushort tile[64 * 72];
  int bid = blockIdx.x;
  int t = threadIdx.x;

  if (bid < 2048) {                      // ---- span gather
    int sub = t >> 7, tt = t & 127;
    int l = bid * 2 + sub;
    int b = bids[l], s0 = begins[l], s1 = ends[l];
    const float4* hidv = (const float4*)hidden;
    float4 lf = hidv[((size_t)(s0 - 1) * B + b) * 128 + tt];
    float4 rf = hidv[((size_t)s1 * B + b) * 128 + tt];
    float4 m = make_float4(0.f, 0.f, 0.f, 0.f);
    int len = s1 - s0;
    #pragma unroll
    for (int j = 0; j < SMAX; ++j) {
      float4 g = hidv[((size_t)(s0 + j) * B + b) * 128 + tt];
      if (j < len) { m.x += g.x; m.y += g.y; m.z += g.z; m.w += g.w; }
    }
    float inv = 1.0f / (float)len;
    ushort* sp = spanb + (size_t)l * 1536;
    ushort4 u;
    u.x = f2bf(lf.x); u.y = f2bf(lf.y); u.z = f2bf(lf.z); u.w = f2bf(lf.w);
    *(ushort4*)&sp[tt * 4] = u;
    u.x = f2bf(m.x * inv); u.y = f2bf(m.y * inv);
    u.z = f2bf(m.z * inv); u.w = f2bf(m.w * inv);
    *(ushort4*)&sp[512 + tt * 4] = u;
    u.x = f2bf(rf.x); u.y = f2bf(rf.y); u.z = f2bf(rf.z); u.w = f2bf(rf.w);
    *(ushort4*)&sp[1024 + tt * 4] = u;
    return;
  }

  // ---- transpose+cast tiles
  const float* src; ushort* dst; int K, N, n0, k0; bool wo = false;
  if (bid < 2144) {
    int u = bid - 2048; src = W1; dst = W1b; K = 1536; N = 256;
    n0 = (u & 3) * 64; k0 = (u >> 2) * 64;
  } else if (bid < 2160) {
    int u = bid - 2144; src = W2; dst = W2b; K = 256; N = 256;
    n0 = (u & 3) * 64; k0 = (u >> 2) * 64;
  } else {
    int u = bid - 2160; src = Wo; dst = Wob; K = 256; N = V;
    n0 = (u % 500) * 64; k0 = (u / 500) * 64; wo = true;
  }
  #pragma unroll
  for (int p = 0; p < 16; ++p) {
    int k = p * 4 + (t >> 6);
    int n = t & 63;
    tile[n * 72 + k] = f2bf(src[(size_t)(k0 + k) * N + n0 + n]);
  }
  __syncthreads();
  if (!wo) {
    #pragma unroll
    for (int p = 0; p < 2; ++p) {
      int idx = p * 256 + t;
      int n = idx >> 3, c = idx & 7;
      *(uint4*)&dst[(size_t)(n0 + n) * K + k0 + c * 8] =
          *(const uint4*)&tile[n * 72 + c * 8];
    }
  } else {
    // fragment-major (verified bijection), coalesced emission:
    //   f = (((c*2+kh)*4+k4)*8+nt)*64 + lq*16 + lr
    //   v = c*128 + nt*16 + lr,  k = kh*128 + k4*32 + lq*8 + e
    // idx = fr*64 + slot: fr picks (ntl, k4l), slot = lq*16+lr walks one
    // frag's 64 consecutive 16B slots -> full 1KB bursts per 64 threads.
    #pragma unroll
    for (int p = 0; p < 2; ++p) {
      int idx = p * 256 + t;             // 512 uint4 per tile
      int fr = idx >> 6, slot = idx & 63;
      int ntl = fr & 3, k4l = fr >> 2;
      int lq = slot >> 4, lr = slot & 15;
      int v = n0 + ntl * 16 + lr;
      int k = k0 + k4l * 32 + lq * 8;
      int c = v >> 7, nt = (v >> 4) & 7;
      int kh = k >> 7, k4 = (k >> 5) & 3;
      size_t f = ((((size_t)c * 2 + kh) * 4 + k4) * 8 + nt) * 64 + lq * 16 + lr;
      *(uint4*)&dst[f * 8] =
          *(const uint4*)&tile[(ntl * 16 + lr) * 72 + k4l * 32 + lq * 8];
    }
  }
}

// ---------------------------------------------------------------- kernel C
// MFMA MLP: featb = bf16( sigmoid(spanb@W1+b1) @ W2 + b2 )
// 256 blocks x 16 labels, A/B direct from global (L2-hot), LDS only for
// the H transpose. Also zeroes `out` (replaces the memset launch).
__global__ __launch_bounds__(256) void feat_mfma_kernel(
    const ushort* __restrict__ spanb, const ushort* __restrict__ W1b,
    const float* __restrict__ b1, const ushort* __restrict__ W2b,
    const float* __restrict__ b2, ushort* __restrict__ featb,
    float* __restrict__ out) {
  __shared__ ushort Hs[16 * 264];
  int tid = threadIdx.x;
  if (blockIdx.x == 0 && tid == 0) *out = 0.f;   // zero accumulator output
  int w = tid >> 6, lane = tid & 63;
  int lr = lane & 15, lq = lane >> 4;
  int l0 = blockIdx.x * 16;

  const short8* arow = (const short8*)(spanb + (size_t)(l0 + lr) * 1536 + lq * 8);
  const short8* brow[4];
  #pragma unroll
  for (int nt = 0; nt < 4; ++nt)
    brow[nt] = (const short8*)(W1b + (size_t)(w * 64 + nt * 16 + lr) * 1536 + lq * 8);

  float4v acc[4];
  float4v zero = {0.f, 0.f, 0.f, 0.f};
  #pragma unroll
  for (int nt = 0; nt < 4; ++nt) acc[nt] = zero;

  short8 af[2], bf[2][4];
  af[0] = arow[0];
  #pragma unroll
  for (int nt = 0; nt < 4; ++nt) bf[0][nt] = brow[nt][0];

  #pragma unroll
  for (int s = 0; s < 48; ++s) {
    int cur = s & 1, nxt = cur ^ 1;
    if (s < 47) {
      af[nxt] = arow[(s + 1) * 4];
      #pragma unroll
      for (int nt = 0; nt < 4; ++nt) bf[nxt][nt] = brow[nt][(s + 1) * 4];
    }
    #pragma unroll
    for (int nt = 0; nt < 4; ++nt)
      acc[nt] = __builtin_amdgcn_mfma_f32_16x16x32_bf16(
          af[cur], bf[cur][nt], acc[nt], 0, 0, 0);
  }

  {
    #pragma unroll
    for (int nt = 0; nt < 4; ++nt) {
      float b1v = b1[w * 64 + nt * 16 + lr];
      #pragma unroll
      for (int r = 0; r < 4; ++r) {
        int row = lq * 4 + r;
        float h = 1.0f / (1.0f + __expf(-(acc[nt][r] + b1v)));
        Hs[row * 264 + w * 64 + nt * 16 + lr] = f2bf(h);
      }
    }
  }
  __syncthreads();

  const short8* wrow[4];
  #pragma unroll
  for (int nt = 0; nt < 4; ++nt)
    wrow[nt] = (const short8*)(W2b + (size_t)(w * 64 + nt * 16 + lr) * 256 + lq * 8);

  float4v acc2[4];
  #pragma unroll
  for (int nt = 0; nt < 4; ++nt) acc2[nt] = zero;

  short8 bf2[2][4];
  #pragma unroll
  for (int nt = 0; nt < 4; ++nt) bf2[0][nt] = wrow[nt][0];

  #pragma unroll
  for (int s = 0; s < 8; ++s) {
    int cur = s & 1, nxt = cur ^ 1;
    if (s < 7) {
      #pragma unroll
      for (int nt = 0; nt < 4; ++nt) bf2[nxt][nt] = wrow[nt][(s + 1) * 4];
    }
    short8 af2 = *(const short8*)&Hs[lr * 264 + s * 32 + lq * 8];
    #pragma unroll
    for (int nt = 0; nt < 4; ++nt)
      acc2[nt] = __builtin_amdgcn_mfma_f32_16x16x32_bf16(
          af2, bf2[cur][nt], acc2[nt], 0, 0, 0);
  }

  {
    #pragma unroll
    for (int nt = 0; nt < 4; ++nt) {
      float b2v = b2[w * 64 + nt * 16 + lr];
      #pragma unroll
      for (int r = 0; r < 4; ++r) {
        int row = lq * 4 + r;
        int col = w * 64 + nt * 16 + lr;
        featb[(size_t)(l0 + row) * 256 + col] = f2bf(acc2[nt][r] + b2v);
      }
    }
  }
}

// ---------------------------------------------------------------- kernel D
// logits + sumexp partials. EXACT R7 structure (proven 98.4us). R10's
// atomicAdd epilogue cost +10us (WRITE 4->16MB RMW) -> reverted to pz
// float4 stores (full 64B lines).
__global__ __launch_bounds__(512, 4) void logits2_kernel(
    const ushort* __restrict__ featb, const ushort* __restrict__ Wob,
    const float* __restrict__ bo, float* __restrict__ pz) {
  __shared__ ushort Blds[2][16384];      // 2 x 32 KB halves (frag-major)
  int tid = threadIdx.x;
  int w = tid >> 6, lane = tid & 63;
  int lr = lane & 15, lq = lane >> 4;
  int l0 = blockIdx.x * 256;
  int v0 = blockIdx.y * 128;

  // per-mt global A pointers; k-step advance = 32 ushorts = 4 short8
  const short8* aptr[2];
  #pragma unroll
  for (int mt = 0; mt < 2; ++mt)
    aptr[mt] = (const short8*)(featb +
        (size_t)(l0 + w * 32 + mt * 16 + lr) * 256 + lq * 8);

  float4v acc[2][8];
  float4v zero = {0.f, 0.f, 0.f, 0.f};
  #pragma unroll
  for (int mt = 0; mt < 2; ++mt)
    #pragma unroll
    for (int nt = 0; nt < 8; ++nt) acc[mt][nt] = zero;

  short8 af[2][2];
  #pragma unroll
  for (int mt = 0; mt < 2; ++mt) af[0][mt] = aptr[mt][0];

#define STAGE_HALF(buf, kh)                                                   \
  {                                                                           \
    const uint4* src4 = (const uint4*)(Wob +                                  \
        (size_t)blockIdx.y * 32768 + (size_t)(kh) * 16384);                   \
    _Pragma("unroll")                                                         \
    for (int p = 0; p < 4; ++p) {                                             \
      int idx = p * 512 + tid;                                                \
      __builtin_amdgcn_global_load_lds(                                       \
          (const __attribute__((address_space(1))) unsigned int*)(src4 + idx),\
          (__attribute__((address_space(3))) unsigned int*)                   \
              &Blds[buf][(size_t)idx * 8],                                    \
          16, 0, 0);                                                          \
    }                                                                         \
  }

#define KG_BLOCK(buf, kh)                                                     \
  _Pragma("unroll")                                                           \
  for (int k4 = 0; k4 < 4; ++k4) {                                            \
    int kg = (kh) * 4 + k4;                                                   \
    int cur = kg & 1, nxt = cur ^ 1;                                          \
    if (kg < 7) {                                                             \
      _Pragma("unroll")                                                       \
      for (int mt = 0; mt < 2; ++mt)                                          \
        af[nxt][mt] = aptr[mt][(kg + 1) * 4];                                 \
    }                                                                         \
    short8 bf[8];                                                             \
    _Pragma("unroll")                                                         \
    for (int nt = 0; nt < 8; ++nt)                                            \
      bf[nt] = *(const short8*)                                               \
          &Blds[buf][(size_t)(((k4 * 8 + nt) * 64) + lane) * 8];              \
    __builtin_amdgcn_s_setprio(1);                                            \
    _Pragma("unroll")                                                         \
    for (int mt = 0; mt < 2; ++mt)                                            \
      _Pragma("unroll")                                                       \
      for (int nt = 0; nt < 8; ++nt)                                          \
        acc[mt][nt] = __builtin_amdgcn_mfma_f32_16x16x32_bf16(                \
            af[cur][mt], bf[nt], acc[mt][nt], 0, 0, 0);                       \
    __builtin_amdgcn_s_setprio(0);                                            \
  }

  STAGE_HALF(0, 0);                      // stage h0
  __syncthreads();                       // h0 ready
  STAGE_HALF(1, 1);                      // h1 DMA in flight under compute h0
  KG_BLOCK(0, 0);                        // compute h0 (LDS-only)
  __syncthreads();                       // h1 ready (DMA long done)
  KG_BLOCK(1, 1);                        // compute h1

#undef STAGE_HALF
#undef KG_BLOCK

  // epilogue: z[row] = sum_cols exp(logit + bo); pz float4 stores
  float bov[8];
  #pragma unroll
  for (int nt = 0; nt < 8; ++nt)
    bov[nt] = bo[v0 + nt * 16 + lr] * LOG2E;
  float z[2][4];
  #pragma unroll
  for (int mt = 0; mt < 2; ++mt)
    #pragma unroll
    for (int r = 0; r < 4; ++r) z[mt][r] = 0.f;
  #pragma unroll
  for (int mt = 0; mt < 2; ++mt)
    #pragma unroll
    for (int nt = 0; nt < 8; ++nt)
      #pragma unroll
      for (int r = 0; r < 4; ++r)
        z[mt][r] += exp2f(fmaf(acc[mt][nt][r], LOG2E, bov[nt]));
  #pragma unroll
  for (int mt = 0; mt < 2; ++mt)
    #pragma unroll
    for (int r = 0; r < 4; ++r) {
      #pragma unroll
      for (int off = 1; off < 16; off <<= 1)
        z[mt][r] += __shfl_xor(z[mt][r], off);
    }
  if (lr == 0) {
    int ch = blockIdx.y;
    #pragma unroll
    for (int mt = 0; mt < 2; ++mt) {
      float4 v4;
      v4.x = z[mt][0]; v4.y = z[mt][1]; v4.z = z[mt][2]; v4.w = z[mt][3];
      *(float4*)&pz[(size_t)ch * L + l0 + w * 32 + mt * 16 + lq * 4] = v4;
    }
  }
}

// ---------------------------------------------------------------- kernel F
// Final: pz reduce (4-way chunk-split, coalesced, 64 blocks so 25% of CUs
// engaged vs old 16-block reduce) + tag logit + loss + global mean.
__global__ __launch_bounds__(256) void final_kernel(
    const ushort* __restrict__ featb, const ushort* __restrict__ Wob,
    const float* __restrict__ bo, const int* __restrict__ tags,
    const float* __restrict__ pz, float* __restrict__ out) {
  __shared__ float zp[4][64];
  __shared__ float zl[64];
  __shared__ float wsum[4];
  int tid = threadIdx.x;
  int w = tid >> 6, lane = tid & 63;
  int lb = blockIdx.x * 64;

  // phase 1: zsum for 64 labels; wave q sums chunks q, q+4, ...
  {
    float zs = 0.f;
    for (int c = w; c < NCH; c += 4)
      zs += pz[(size_t)c * L + lb + lane];
    zp[w][lane] = zs;
  }
  __syncthreads();
  if (w == 0)
    zl[lane] = zp[0][lane] + zp[1][lane] + zp[2][lane] + zp[3][lane];
  __syncthreads();

  // phase 2: tag dots (frag-major Wob gather), 16 labels per wave
  float psum = 0.f;
  for (int i = 0; i < 16; ++i) {
    int l = lb + w * 16 + i;
    int tg = tags[l];
    int c = tg >> 7, nt = (tg >> 4) & 7, lr = tg & 15;
    int k0 = lane << 2;
    int kh = k0 >> 7, k4 = (k0 >> 5) & 3, lq = (k0 >> 3) & 3, e = k0 & 7;
    size_t f = ((((size_t)c * 2 + kh) * 4 + k4) * 8 + nt) * 64 + lq * 16 + lr;
    ushort4 wa = *(const ushort4*)&Wob[f * 8 + e];
    ushort4 fa = *(const ushort4*)&featb[(size_t)l * 256 + k0];
    float s = bf2f(fa.x) * bf2f(wa.x) + bf2f(fa.y) * bf2f(wa.y) +
              bf2f(fa.z) * bf2f(wa.z) + bf2f(fa.w) * bf2f(wa.w);
    #pragma unroll
    for (int off = 1; off < 64; off <<= 1) s += __shfl_xor(s, off);
    if (lane == 0)
      psum += logf(zl[w * 16 + i]) - (s + bo[tg]);
  }
  if (lane == 0) wsum[w] = psum;
  __syncthreads();
  if (tid == 0) {
    float v = (wsum[0] + wsum[1] + wsum[2] + wsum[3]) *
              (1.0f / (4096.0f + 1e-5f));
    atomicAdd(out, v);
  }
}

// ---------------------------------------------------------------- launch
extern "C" void kernel_launch(void* const* d_in, const int* in_sizes, int n_in,
                              void* d_out, int out_size, void* d_ws,
                              size_t ws_size, hipStream_t stream) {
  const float* hidden = (const float*)d_in[0];
  const int* begins = (const int*)d_in[1];
  const int* ends = (const int*)d_in[2];
  const int* bids = (const int*)d_in[3];
  const int* tags = (const int*)d_in[4];
  const float* W1 = (const float*)d_in[5];
  const float* b1 = (const float*)d_in[6];
  const float* W2 = (const float*)d_in[7];
  const float* b2 = (const float*)d_in[8];
  const float* Wo = (const float*)d_in[9];
  const float* bo = (const float*)d_in[10];
  float* out = (float*)d_out;

  ushort* featb = (ushort*)d_ws;                       // L*256
  ushort* Wob = featb + (size_t)L * 256;               // V*256 (frag-major)
  ushort* spanb = Wob + (size_t)V * 256;               // L*1536
  ushort* W1b = spanb + (size_t)L * 1536;              // 256*1536
  ushort* W2b = W1b + (size_t)256 * 1536;              // 256*256
  // pz (NCH*L f32 = 4.1 MB) aliases spanb (12.6 MB): spanb dead after
  // feat_mfma_kernel; logits2 runs strictly after it in-stream.
  float* pz = (float*)spanb;

  prep_kernel<<<4160, 256, 0, stream>>>(hidden, begins, ends, bids, spanb,
                                        W1, W1b, W2, W2b, Wo, Wob);
  feat_mfma_kernel<<<256, 256, 0, stream>>>(spanb, W1b, b1, W2b, b2, featb,
                                            out);
  logits2_kernel<<<dim3(16, NCH), 512, 0, stream>>>(featb, Wob, bo, pz);
  final_kernel<<<L / 64, 256, 0, stream>>>(featb, Wob, bo, tags, pz, out);
}

// Round 12
// 284.068 us; speedup vs baseline: 1.0269x; 1.0269x over previous
//
#include <hip/hip_runtime.h>
#include <math.h>

#define S 2048
#define B 16
#define H 512
#define L 4096
#define SMAX 16
#define LAB 256
#define V 32000
#define NCH 250          // V / 128 vocab chunks
#define LOG2E 1.44269504f

typedef __attribute__((ext_vector_type(8))) short short8;
typedef __attribute__((ext_vector_type(4))) float float4v;

__device__ inline ushort f2bf(float x) {
  union { float f; unsigned u; } c; c.f = x;
  unsigned r = c.u + 0x7fffu + ((c.u >> 16) & 1u);
  return (ushort)(r >> 16);
}
__device__ inline float bf2f(ushort h) {
  union { unsigned u; float f; } c; c.u = ((unsigned)h) << 16;
  return c.f;
}

// ---------------------------------------------------------------- kernel P
// Fused prep: blocks [0,2048) span gather; [2048,2144) W1 tcast;
// [2144,2160) W2 tcast; [2160,4160) Wo frag-major tcast.
// NOTE (R11 post-mortem): serial span loop and scattered 16B Wo writes are
// the FASTER variants — the R11 "fixes" (predicated 16-row unroll, coalesced
// frag writes) regressed non-logits time 182->193us (extra hidden reads /
// 8-way LDS read conflict). Keep R7-exact.
__global__ __launch_bounds__(256) void prep_kernel(
    const float* __restrict__ hidden, const int* __restrict__ begins,
    const int* __restrict__ ends, const int* __restrict__ bids,
    ushort* __restrict__ spanb, const float* __restrict__ W1,
    ushort* __restrict__ W1b, const float* __restrict__ W2,
    ushort* __restrict__ W2b, const float* __restrict__ Wo,
    ushort* __restrict__ Wob) {
  __shared__ ushort tile[64 * 72];
  int bid = blockIdx.x;
  int t = threadIdx.x;

  if (bid < 2048) {                      // ---- span gather
    int sub = t >> 7, tt = t & 127;
    int l = bid * 2 + sub;
    int b = bids[l], s0 = begins[l], s1 = ends[l];
    const float4* hidv = (const float4*)hidden;
    float4 lf = hidv[((size_t)(s0 - 1) * B + b) * 128 + tt];
    float4 rf = hidv[((size_t)s1 * B + b) * 128 + tt];
    float4 m = make_float4(0.f, 0.f, 0.f, 0.f);
    int len = s1 - s0;
    for (int j = 0; j < len; ++j) {
      float4 g = hidv[((size_t)(s0 + j) * B + b) * 128 + tt];
      m.x += g.x; m.y += g.y; m.z += g.z; m.w += g.w;
    }
    float inv = 1.0f / (float)len;
    ushort* sp = spanb + (size_t)l * 1536;
    ushort4 u;
    u.x = f2bf(lf.x); u.y = f2bf(lf.y); u.z = f2bf(lf.z); u.w = f2bf(lf.w);
    *(ushort4*)&sp[tt * 4] = u;
    u.x = f2bf(m.x * inv); u.y = f2bf(m.y * inv);
    u.z = f2bf(m.z * inv); u.w = f2bf(m.w * inv);
    *(ushort4*)&sp[512 + tt * 4] = u;
    u.x = f2bf(rf.x); u.y = f2bf(rf.y); u.z = f2bf(rf.z); u.w = f2bf(rf.w);
    *(ushort4*)&sp[1024 + tt * 4] = u;
    return;
  }

  // ---- transpose+cast tiles
  const float* src; ushort* dst; int K, N, n0, k0; bool wo = false;
  if (bid < 2144) {
    int u = bid - 2048; src = W1; dst = W1b; K = 1536; N = 256;
    n0 = (u & 3) * 64; k0 = (u >> 2) * 64;
  } else if (bid < 2160) {
    int u = bid - 2144; src = W2; dst = W2b; K = 256; N = 256;
    n0 = (u & 3) * 64; k0 = (u >> 2) * 64;
  } else {
    int u = bid - 2160; src = Wo; dst = Wob; K = 256; N = V;
    n0 = (u % 500) * 64; k0 = (u / 500) * 64; wo = true;
  }
  #pragma unroll
  for (int p = 0; p < 16; ++p) {
    int k = p * 4 + (t >> 6);
    int n = t & 63;
    tile[n * 72 + k] = f2bf(src[(size_t)(k0 + k) * N + n0 + n]);
  }
  __syncthreads();
  if (!wo) {
    #pragma unroll
    for (int p = 0; p < 2; ++p) {
      int idx = p * 256 + t;
      int n = idx >> 3, c = idx & 7;
      *(uint4*)&dst[(size_t)(n0 + n) * K + k0 + c * 8] =
          *(const uint4*)&tile[n * 72 + c * 8];
    }
  } else {
    // fragment-major: f = (((c*2+kh)*4+k4)*8+nt)*64 + lq*16 + lr
    #pragma unroll
    for (int p = 0; p < 2; ++p) {
      int idx = p * 256 + t;
      int n = idx >> 3, c8 = idx & 7;
      int v = n0 + n, k = k0 + c8 * 8;
      int c = v >> 7, nt = (v >> 4) & 7, lr = v & 15;
      int kh = k >> 7, k4 = (k >> 5) & 3, lq = (k >> 3) & 3;
      size_t f = ((((size_t)c * 2 + kh) * 4 + k4) * 8 + nt) * 64 + lq * 16 + lr;
      *(uint4*)&dst[f * 8] = *(const uint4*)&tile[n * 72 + c8 * 8];
    }
  }
}

// ---------------------------------------------------------------- kernel C
// MFMA MLP: featb = bf16( sigmoid(spanb@W1+b1) @ W2 + b2 )
// 256 blocks x 16 labels, A/B direct from global (L2-hot), LDS only for
// the H transpose. Also zeroes `out` (replaces the memset launch).
__global__ __launch_bounds__(256) void feat_mfma_kernel(
    const ushort* __restrict__ spanb, const ushort* __restrict__ W1b,
    const float* __restrict__ b1, const ushort* __restrict__ W2b,
    const float* __restrict__ b2, ushort* __restrict__ featb,
    float* __restrict__ out) {
  __shared__ ushort Hs[16 * 264];
  int tid = threadIdx.x;
  if (blockIdx.x == 0 && tid == 0) *out = 0.f;   // zero accumulator output
  int w = tid >> 6, lane = tid & 63;
  int lr = lane & 15, lq = lane >> 4;
  int l0 = blockIdx.x * 16;

  const short8* arow = (const short8*)(spanb + (size_t)(l0 + lr) * 1536 + lq * 8);
  const short8* brow[4];
  #pragma unroll
  for (int nt = 0; nt < 4; ++nt)
    brow[nt] = (const short8*)(W1b + (size_t)(w * 64 + nt * 16 + lr) * 1536 + lq * 8);

  float4v acc[4];
  float4v zero = {0.f, 0.f, 0.f, 0.f};
  #pragma unroll
  for (int nt = 0; nt < 4; ++nt) acc[nt] = zero;

  short8 af[2], bf[2][4];
  af[0] = arow[0];
  #pragma unroll
  for (int nt = 0; nt < 4; ++nt) bf[0][nt] = brow[nt][0];

  #pragma unroll
  for (int s = 0; s < 48; ++s) {
    int cur = s & 1, nxt = cur ^ 1;
    if (s < 47) {
      af[nxt] = arow[(s + 1) * 4];
      #pragma unroll
      for (int nt = 0; nt < 4; ++nt) bf[nxt][nt] = brow[nt][(s + 1) * 4];
    }
    #pragma unroll
    for (int nt = 0; nt < 4; ++nt)
      acc[nt] = __builtin_amdgcn_mfma_f32_16x16x32_bf16(
          af[cur], bf[cur][nt], acc[nt], 0, 0, 0);
  }

  {
    #pragma unroll
    for (int nt = 0; nt < 4; ++nt) {
      float b1v = b1[w * 64 + nt * 16 + lr];
      #pragma unroll
      for (int r = 0; r < 4; ++r) {
        int row = lq * 4 + r;
        float h = 1.0f / (1.0f + __expf(-(acc[nt][r] + b1v)));
        Hs[row * 264 + w * 64 + nt * 16 + lr] = f2bf(h);
      }
    }
  }
  __syncthreads();

  const short8* wrow[4];
  #pragma unroll
  for (int nt = 0; nt < 4; ++nt)
    wrow[nt] = (const short8*)(W2b + (size_t)(w * 64 + nt * 16 + lr) * 256 + lq * 8);

  float4v acc2[4];
  #pragma unroll
  for (int nt = 0; nt < 4; ++nt) acc2[nt] = zero;

  short8 bf2[2][4];
  #pragma unroll
  for (int nt = 0; nt < 4; ++nt) bf2[0][nt] = wrow[nt][0];

  #pragma unroll
  for (int s = 0; s < 8; ++s) {
    int cur = s & 1, nxt = cur ^ 1;
    if (s < 7) {
      #pragma unroll
      for (int nt = 0; nt < 4; ++nt) bf2[nxt][nt] = wrow[nt][(s + 1) * 4];
    }
    short8 af2 = *(const short8*)&Hs[lr * 264 + s * 32 + lq * 8];
    #pragma unroll
    for (int nt = 0; nt < 4; ++nt)
      acc2[nt] = __builtin_amdgcn_mfma_f32_16x16x32_bf16(
          af2, bf2[cur][nt], acc2[nt], 0, 0, 0);
  }

  {
    #pragma unroll
    for (int nt = 0; nt < 4; ++nt) {
      float b2v = b2[w * 64 + nt * 16 + lr];
      #pragma unroll
      for (int r = 0; r < 4; ++r) {
        int row = lq * 4 + r;
        int col = w * 64 + nt * 16 + lr;
        featb[(size_t)(l0 + row) * 256 + col] = f2bf(acc2[nt][r] + b2v);
      }
    }
  }
}

// ---------------------------------------------------------------- kernel D
// logits + sumexp partials. R7-exact (proven 98.4us; best of 6 structural
// variants): 512 threads, 256 labels x 128 vocab, double-buffered 32KB
// halves, linear global_load_lds staging, frag-major Wob, conflict-free
// ds_read, pz float4 stores.
__global__ __launch_bounds__(512, 4) void logits2_kernel(
    const ushort* __restrict__ featb, const ushort* __restrict__ Wob,
    const float* __restrict__ bo, float* __restrict__ pz) {
  __shared__ ushort Blds[2][16384];      // 2 x 32 KB halves (frag-major)
  int tid = threadIdx.x;
  int w = tid >> 6, lane = tid & 63;
  int lr = lane & 15, lq = lane >> 4;
  int l0 = blockIdx.x * 256;
  int v0 = blockIdx.y * 128;

  // per-mt global A pointers; k-step advance = 32 ushorts = 4 short8
  const short8* aptr[2];
  #pragma unroll
  for (int mt = 0; mt < 2; ++mt)
    aptr[mt] = (const short8*)(featb +
        (size_t)(l0 + w * 32 + mt * 16 + lr) * 256 + lq * 8);

  float4v acc[2][8];
  float4v zero = {0.f, 0.f, 0.f, 0.f};
  #pragma unroll
  for (int mt = 0; mt < 2; ++mt)
    #pragma unroll
    for (int nt = 0; nt < 8; ++nt) acc[mt][nt] = zero;

  short8 af[2][2];
  #pragma unroll
  for (int mt = 0; mt < 2; ++mt) af[0][mt] = aptr[mt][0];

#define STAGE_HALF(buf, kh)                                                   \
  {                                                                           \
    const uint4* src4 = (const uint4*)(Wob +                                  \
        (size_t)blockIdx.y * 32768 + (size_t)(kh) * 16384);                   \
    _Pragma("unroll")                                                         \
    for (int p = 0; p < 4; ++p) {                                             \
      int idx = p * 512 + tid;                                                \
      __builtin_amdgcn_global_load_lds(                                       \
          (const __attribute__((address_space(1))) unsigned int*)(src4 + idx),\
          (__attribute__((address_space(3))) unsigned int*)                   \
              &Blds[buf][(size_t)idx * 8],                                    \
          16, 0, 0);                                                          \
    }                                                                         \
  }

#define KG_BLOCK(buf, kh)                                                     \
  _Pragma("unroll")                                                           \
  for (int k4 = 0; k4 < 4; ++k4) {                                            \
    int kg = (kh) * 4 + k4;                                                   \
    int cur = kg & 1, nxt = cur ^ 1;                                          \
    if (kg < 7) {                                                             \
      _Pragma("unroll")                                                       \
      for (int mt = 0; mt < 2; ++mt)                                          \
        af[nxt][mt] = aptr[mt][(kg + 1) * 4];                                 \
    }                                                                         \
    short8 bf[8];                                                             \
    _Pragma("unroll")                                                         \
    for (int nt = 0; nt < 8; ++nt)                                            \
      bf[nt] = *(const short8*)                                               \
          &Blds[buf][(size_t)(((k4 * 8 + nt) * 64) + lane) * 8];              \
    __builtin_amdgcn_s_setprio(1);                                            \
    _Pragma("unroll")                                                         \
    for (int mt = 0; mt < 2; ++mt)                                            \
      _Pragma("unroll")                                                       \
      for (int nt = 0; nt < 8; ++nt)                                          \
        acc[mt][nt] = __builtin_amdgcn_mfma_f32_16x16x32_bf16(                \
            af[cur][mt], bf[nt], acc[mt][nt], 0, 0, 0);                       \
    __builtin_amdgcn_s_setprio(0);                                            \
  }

  STAGE_HALF(0, 0);                      // stage h0
  __syncthreads();                       // h0 ready
  STAGE_HALF(1, 1);                      // h1 DMA in flight under compute h0
  KG_BLOCK(0, 0);                        // compute h0 (LDS-only)
  __syncthreads();                       // h1 ready (DMA long done)
  KG_BLOCK(1, 1);                        // compute h1

#undef STAGE_HALF
#undef KG_BLOCK

  // epilogue: z[row] = sum_cols exp(logit + bo), no max (logits bounded)
  // bov loaded HERE to keep in-loop arch regs <= 64
  float bov[8];
  #pragma unroll
  for (int nt = 0; nt < 8; ++nt)
    bov[nt] = bo[v0 + nt * 16 + lr] * LOG2E;
  float z[2][4];
  #pragma unroll
  for (int mt = 0; mt < 2; ++mt)
    #pragma unroll
    for (int r = 0; r < 4; ++r) z[mt][r] = 0.f;
  #pragma unroll
  for (int mt = 0; mt < 2; ++mt)
    #pragma unroll
    for (int nt = 0; nt < 8; ++nt)
      #pragma unroll
      for (int r = 0; r < 4; ++r)
        z[mt][r] += exp2f(fmaf(acc[mt][nt][r], LOG2E, bov[nt]));
  #pragma unroll
  for (int mt = 0; mt < 2; ++mt)
    #pragma unroll
    for (int r = 0; r < 4; ++r) {
      #pragma unroll
      for (int off = 1; off < 16; off <<= 1)
        z[mt][r] += __shfl_xor(z[mt][r], off);
    }
  if (lr == 0) {
    int ch = blockIdx.y;
    #pragma unroll
    for (int mt = 0; mt < 2; ++mt) {
      float4 v4;
      v4.x = z[mt][0]; v4.y = z[mt][1]; v4.z = z[mt][2]; v4.w = z[mt][3];
      *(float4*)&pz[(size_t)ch * L + l0 + w * 32 + mt * 16 + lq * 4] = v4;
    }
  }
}

// ---------------------------------------------------------------- kernel E
// Exact tag logit from fragment-major Wob (same bf16 values as pz path).
__global__ __launch_bounds__(256) void tag_kernel(
    const ushort* __restrict__ featb, const ushort* __restrict__ Wob,
    const float* __restrict__ bo, const int* __restrict__ tags,
    float* __restrict__ tagl) {
  int l = blockIdx.x * 4 + (threadIdx.x >> 6);
  int lane = threadIdx.x & 63;
  int tg = tags[l];
  int c = tg >> 7, nt = (tg >> 4) & 7, lr = tg & 15;
  int k0 = lane << 2;
  int kh = k0 >> 7, k4 = (k0 >> 5) & 3, lq = (k0 >> 3) & 3, e = k0 & 7;
  size_t f = ((((size_t)c * 2 + kh) * 4 + k4) * 8 + nt) * 64 + lq * 16 + lr;
  ushort4 wa = *(const ushort4*)&Wob[f * 8 + e];
  ushort4 fa = *(const ushort4*)&featb[(size_t)l * 256 + k0];
  float s = bf2f(fa.x) * bf2f(wa.x) + bf2f(fa.y) * bf2f(wa.y) +
            bf2f(fa.z) * bf2f(wa.z) + bf2f(fa.w) * bf2f(wa.w);
  #pragma unroll
  for (int off = 1; off < 64; off <<= 1) s += __shfl_xor(s, off);
  if (lane == 0) tagl[l] = s + bo[tg];
}

// ---------------------------------------------------------------- kernel F
__global__ __launch_bounds__(256) void reduce_kernel(
    const float* __restrict__ pz, const float* __restrict__ tagl,
    float* __restrict__ out) {
  int l = blockIdx.x * 256 + threadIdx.x;
  float z = 0.f;
  #pragma unroll 5
  for (int c = 0; c < NCH; ++c) z += pz[(size_t)c * L + l];
  float per = logf(z) - tagl[l];
  float v = per * (1.0f / (4096.0f + 1e-5f));
  #pragma unroll
  for (int off = 1; off < 64; off <<= 1) v += __shfl_xor(v, off);
  __shared__ float wsum[4];
  if ((threadIdx.x & 63) == 0) wsum[threadIdx.x >> 6] = v;
  __syncthreads();
  if (threadIdx.x == 0)
    atomicAdd(out, wsum[0] + wsum[1] + wsum[2] + wsum[3]);
}

// ---------------------------------------------------------------- launch
extern "C" void kernel_launch(void* const* d_in, const int* in_sizes, int n_in,
                              void* d_out, int out_size, void* d_ws,
                              size_t ws_size, hipStream_t stream) {
  const float* hidden = (const float*)d_in[0];
  const int* begins = (const int*)d_in[1];
  const int* ends = (const int*)d_in[2];
  const int* bids = (const int*)d_in[3];
  const int* tags = (const int*)d_in[4];
  const float* W1 = (const float*)d_in[5];
  const float* b1 = (const float*)d_in[6];
  const float* W2 = (const float*)d_in[7];
  const float* b2 = (const float*)d_in[8];
  const float* Wo = (const float*)d_in[9];
  const float* bo = (const float*)d_in[10];
  float* out = (float*)d_out;

  ushort* featb = (ushort*)d_ws;                       // L*256
  ushort* Wob = featb + (size_t)L * 256;               // V*256 (frag-major)
  ushort* spanb = Wob + (size_t)V * 256;               // L*1536
  ushort* W1b = spanb + (size_t)L * 1536;              // 256*1536
  ushort* W2b = W1b + (size_t)256 * 1536;              // 256*256
  // pz (NCH*L f32 = 4.1 MB) aliases spanb (12.6 MB): spanb dead after
  // feat_mfma_kernel; logits2 runs strictly after it in-stream.
  float* pz = (float*)spanb;
  float* tagl = (float*)(W2b + (size_t)256 * 256);     // L

  prep_kernel<<<4160, 256, 0, stream>>>(hidden, begins, ends, bids, spanb,
                                        W1, W1b, W2, W2b, Wo, Wob);
  feat_mfma_kernel<<<256, 256, 0, stream>>>(spanb, W1b, b1, W2b, b2, featb,
                                            out);
  logits2_kernel<<<dim3(16, NCH), 512, 0, stream>>>(featb, Wob, bo, pz);
  tag_kernel<<<L / 4, 256, 0, stream>>>(featb, Wob, bo, tags, tagl);
  reduce_kernel<<<L / 256, 256, 0, stream>>>(pz, tagl, out);
}

// Round 13
// 271.599 us; speedup vs baseline: 1.0741x; 1.0459x over previous
//
#include <hip/hip_runtime.h>
#include <math.h>

#define S 2048
#define B 16
#define H 512
#define L 4096
#define SMAX 16
#define LAB 256
#define V 32000
#define NCH 250          // V / 128 vocab chunks
#define LOG2E 1.44269504f

typedef __attribute__((ext_vector_type(8))) short short8;
typedef __attribute__((ext_vector_type(4))) float float4v;

__device__ inline ushort f2bf(float x) {
  union { float f; unsigned u; } c; c.f = x;
  unsigned r = c.u + 0x7fffu + ((c.u >> 16) & 1u);
  return (ushort)(r >> 16);
}
__device__ inline float bf2f(ushort h) {
  union { unsigned u; float f; } c; c.u = ((unsigned)h) << 16;
  return c.f;
}

// ---------------------------------------------------------------- kernel P
// Fused prep: blocks [0,2048) span gather; [2048,2144) W1 tcast;
// [2144,2160) W2 tcast; [2160,4160) Wo frag-major tcast.
// R11 post-mortem: serial span loop and scattered 16B Wo writes are the
// FASTER variants (R11's "fixes" regressed 182->193us). R7-exact.
__global__ __launch_bounds__(256) void prep_kernel(
    const float* __restrict__ hidden, const int* __restrict__ begins,
    const int* __restrict__ ends, const int* __restrict__ bids,
    ushort* __restrict__ spanb, const float* __restrict__ W1,
    ushort* __restrict__ W1b, const float* __restrict__ W2,
    ushort* __restrict__ W2b, const float* __restrict__ Wo,
    ushort* __restrict__ Wob) {
  __shared__ ushort tile[64 * 72];
  int bid = blockIdx.x;
  int t = threadIdx.x;

  if (bid < 2048) {                      // ---- span gather
    int sub = t >> 7, tt = t & 127;
    int l = bid * 2 + sub;
    int b = bids[l], s0 = begins[l], s1 = ends[l];
    const float4* hidv = (const float4*)hidden;
    float4 lf = hidv[((size_t)(s0 - 1) * B + b) * 128 + tt];
    float4 rf = hidv[((size_t)s1 * B + b) * 128 + tt];
    float4 m = make_float4(0.f, 0.f, 0.f, 0.f);
    int len = s1 - s0;
    for (int j = 0; j < len; ++j) {
      float4 g = hidv[((size_t)(s0 + j) * B + b) * 128 + tt];
      m.x += g.x; m.y += g.y; m.z += g.z; m.w += g.w;
    }
    float inv = 1.0f / (float)len;
    ushort* sp = spanb + (size_t)l * 1536;
    ushort4 u;
    u.x = f2bf(lf.x); u.y = f2bf(lf.y); u.z = f2bf(lf.z); u.w = f2bf(lf.w);
    *(ushort4*)&sp[tt * 4] = u;
    u.x = f2bf(m.x * inv); u.y = f2bf(m.y * inv);
    u.z = f2bf(m.z * inv); u.w = f2bf(m.w * inv);
    *(ushort4*)&sp[512 + tt * 4] = u;
    u.x = f2bf(rf.x); u.y = f2bf(rf.y); u.z = f2bf(rf.z); u.w = f2bf(rf.w);
    *(ushort4*)&sp[1024 + tt * 4] = u;
    return;
  }

  // ---- transpose+cast tiles
  const float* src; ushort* dst; int K, N, n0, k0; bool wo = false;
  if (bid < 2144) {
    int u = bid - 2048; src = W1; dst = W1b; K = 1536; N = 256;
    n0 = (u & 3) * 64; k0 = (u >> 2) * 64;
  } else if (bid < 2160) {
    int u = bid - 2144; src = W2; dst = W2b; K = 256; N = 256;
    n0 = (u & 3) * 64; k0 = (u >> 2) * 64;
  } else {
    int u = bid - 2160; src = Wo; dst = Wob; K = 256; N = V;
    n0 = (u % 500) * 64; k0 = (u / 500) * 64; wo = true;
  }
  #pragma unroll
  for (int p = 0; p < 16; ++p) {
    int k = p * 4 + (t >> 6);
    int n = t & 63;
    tile[n * 72 + k] = f2bf(src[(size_t)(k0 + k) * N + n0 + n]);
  }
  __syncthreads();
  if (!wo) {
    #pragma unroll
    for (int p = 0; p < 2; ++p) {
      int idx = p * 256 + t;
      int n = idx >> 3, c = idx & 7;
      *(uint4*)&dst[(size_t)(n0 + n) * K + k0 + c * 8] =
          *(const uint4*)&tile[n * 72 + c * 8];
    }
  } else {
    // fragment-major: f = (((c*2+kh)*4+k4)*8+nt)*64 + lq*16 + lr
    #pragma unroll
    for (int p = 0; p < 2; ++p) {
      int idx = p * 256 + t;
      int n = idx >> 3, c8 = idx & 7;
      int v = n0 + n, k = k0 + c8 * 8;
      int c = v >> 7, nt = (v >> 4) & 7, lr = v & 15;
      int kh = k >> 7, k4 = (k >> 5) & 3, lq = (k >> 3) & 3;
      size_t f = ((((size_t)c * 2 + kh) * 4 + k4) * 8 + nt) * 64 + lq * 16 + lr;
      *(uint4*)&dst[f * 8] = *(const uint4*)&tile[n * 72 + c8 * 8];
    }
  }
}

// ---------------------------------------------------------------- kernel C
// MFMA MLP: featb = bf16( sigmoid(spanb@W1+b1) @ W2 + b2 )
// 256 blocks x 16 labels, A/B direct from global (L2-hot), LDS only for
// the H transpose. Also zeroes `out` (replaces the memset launch).
__global__ __launch_bounds__(256) void feat_mfma_kernel(
    const ushort* __restrict__ spanb, const ushort* __restrict__ W1b,
    const float* __restrict__ b1, const ushort* __restrict__ W2b,
    const float* __restrict__ b2, ushort* __restrict__ featb,
    float* __restrict__ out) {
  __shared__ ushort Hs[16 * 264];
  int tid = threadIdx.x;
  if (blockIdx.x == 0 && tid == 0) *out = 0.f;   // zero accumulator output
  int w = tid >> 6, lane = tid & 63;
  int lr = lane & 15, lq = lane >> 4;
  int l0 = blockIdx.x * 16;

  const short8* arow = (const short8*)(spanb + (size_t)(l0 + lr) * 1536 + lq * 8);
  const short8* brow[4];
  #pragma unroll
  for (int nt = 0; nt < 4; ++nt)
    brow[nt] = (const short8*)(W1b + (size_t)(w * 64 + nt * 16 + lr) * 1536 + lq * 8);

  float4v acc[4];
  float4v zero = {0.f, 0.f, 0.f, 0.f};
  #pragma unroll
  for (int nt = 0; nt < 4; ++nt) acc[nt] = zero;

  short8 af[2], bf[2][4];
  af[0] = arow[0];
  #pragma unroll
  for (int nt = 0; nt < 4; ++nt) bf[0][nt] = brow[nt][0];

  #pragma unroll
  for (int s = 0; s < 48; ++s) {
    int cur = s & 1, nxt = cur ^ 1;
    if (s < 47) {
      af[nxt] = arow[(s + 1) * 4];
      #pragma unroll
      for (int nt = 0; nt < 4; ++nt) bf[nxt][nt] = brow[nt][(s + 1) * 4];
    }
    #pragma unroll
    for (int nt = 0; nt < 4; ++nt)
      acc[nt] = __builtin_amdgcn_mfma_f32_16x16x32_bf16(
          af[cur], bf[cur][nt], acc[nt], 0, 0, 0);
  }

  {
    #pragma unroll
    for (int nt = 0; nt < 4; ++nt) {
      float b1v = b1[w * 64 + nt * 16 + lr];
      #pragma unroll
      for (int r = 0; r < 4; ++r) {
        int row = lq * 4 + r;
        float h = 1.0f / (1.0f + __expf(-(acc[nt][r] + b1v)));
        Hs[row * 264 + w * 64 + nt * 16 + lr] = f2bf(h);
      }
    }
  }
  __syncthreads();

  const short8* wrow[4];
  #pragma unroll
  for (int nt = 0; nt < 4; ++nt)
    wrow[nt] = (const short8*)(W2b + (size_t)(w * 64 + nt * 16 + lr) * 256 + lq * 8);

  float4v acc2[4];
  #pragma unroll
  for (int nt = 0; nt < 4; ++nt) acc2[nt] = zero;

  short8 bf2[2][4];
  #pragma unroll
  for (int nt = 0; nt < 4; ++nt) bf2[0][nt] = wrow[nt][0];

  #pragma unroll
  for (int s = 0; s < 8; ++s) {
    int cur = s & 1, nxt = cur ^ 1;
    if (s < 7) {
      #pragma unroll
      for (int nt = 0; nt < 4; ++nt) bf2[nxt][nt] = wrow[nt][(s + 1) * 4];
    }
    short8 af2 = *(const short8*)&Hs[lr * 264 + s * 32 + lq * 8];
    #pragma unroll
    for (int nt = 0; nt < 4; ++nt)
      acc2[nt] = __builtin_amdgcn_mfma_f32_16x16x32_bf16(
          af2, bf2[cur][nt], acc2[nt], 0, 0, 0);
  }

  {
    #pragma unroll
    for (int nt = 0; nt < 4; ++nt) {
      float b2v = b2[w * 64 + nt * 16 + lr];
      #pragma unroll
      for (int r = 0; r < 4; ++r) {
        int row = lq * 4 + r;
        int col = w * 64 + nt * 16 + lr;
        featb[(size_t)(l0 + row) * 256 + col] = f2bf(acc2[nt][r] + b2v);
      }
    }
  }
}

// ---------------------------------------------------------------- kernel D
// logits + sumexp partials. R7-exact (proven 98.4us; best of 6 structural
// variants): 512 threads, 256 labels x 128 vocab, double-buffered 32KB
// halves, linear global_load_lds staging, frag-major Wob, conflict-free
// ds_read, pz float4 stores.
__global__ __launch_bounds__(512, 4) void logits2_kernel(
    const ushort* __restrict__ featb, const ushort* __restrict__ Wob,
    const float* __restrict__ bo, float* __restrict__ pz) {
  __shared__ ushort Blds[2][16384];      // 2 x 32 KB halves (frag-major)
  int tid = threadIdx.x;
  int w = tid >> 6, lane = tid & 63;
  int lr = lane & 15, lq = lane >> 4;
  int l0 = blockIdx.x * 256;
  int v0 = blockIdx.y * 128;

  // per-mt global A pointers; k-step advance = 32 ushorts = 4 short8
  const short8* aptr[2];
  #pragma unroll
  for (int mt = 0; mt < 2; ++mt)
    aptr[mt] = (const short8*)(featb +
        (size_t)(l0 + w * 32 + mt * 16 + lr) * 256 + lq * 8);

  float4v acc[2][8];
  float4v zero = {0.f, 0.f, 0.f, 0.f};
  #pragma unroll
  for (int mt = 0; mt < 2; ++mt)
    #pragma unroll
    for (int nt = 0; nt < 8; ++nt) acc[mt][nt] = zero;

  short8 af[2][2];
  #pragma unroll
  for (int mt = 0; mt < 2; ++mt) af[0][mt] = aptr[mt][0];

#define STAGE_HALF(buf, kh)                                                   \
  {                                                                           \
    const uint4* src4 = (const uint4*)(Wob +                                  \
        (size_t)blockIdx.y * 32768 + (size_t)(kh) * 16384);                   \
    _Pragma("unroll")                                                         \
    for (int p = 0; p < 4; ++p) {                                             \
      int idx = p * 512 + tid;                                                \
      __builtin_amdgcn_global_load_lds(                                       \
          (const __attribute__((address_space(1))) unsigned int*)(src4 + idx),\
          (__attribute__((address_space(3))) unsigned int*)                   \
              &Blds[buf][(size_t)idx * 8],                                    \
          16, 0, 0);                                                          \
    }                                                                         \
  }

#define KG_BLOCK(buf, kh)                                                     \
  _Pragma("unroll")                                                           \
  for (int k4 = 0; k4 < 4; ++k4) {                                            \
    int kg = (kh) * 4 + k4;                                                   \
    int cur = kg & 1, nxt = cur ^ 1;                                          \
    if (kg < 7) {                                                             \
      _Pragma("unroll")                                                       \
      for (int mt = 0; mt < 2; ++mt)                                          \
        af[nxt][mt] = aptr[mt][(kg + 1) * 4];                                 \
    }                                                                         \
    short8 bf[8];                                                             \
    _Pragma("unroll")                                                         \
    for (int nt = 0; nt < 8; ++nt)                                            \
      bf[nt] = *(const short8*)                                               \
          &Blds[buf][(size_t)(((k4 * 8 + nt) * 64) + lane) * 8];              \
    __builtin_amdgcn_s_setprio(1);                                            \
    _Pragma("unroll")                                                         \
    for (int mt = 0; mt < 2; ++mt)                                            \
      _Pragma("unroll")                                                       \
      for (int nt = 0; nt < 8; ++nt)                                          \
        acc[mt][nt] = __builtin_amdgcn_mfma_f32_16x16x32_bf16(                \
            af[cur][mt], bf[nt], acc[mt][nt], 0, 0, 0);                       \
    __builtin_amdgcn_s_setprio(0);                                            \
  }

  STAGE_HALF(0, 0);                      // stage h0
  __syncthreads();                       // h0 ready
  STAGE_HALF(1, 1);                      // h1 DMA in flight under compute h0
  KG_BLOCK(0, 0);                        // compute h0 (LDS-only)
  __syncthreads();                       // h1 ready (DMA long done)
  KG_BLOCK(1, 1);                        // compute h1

#undef STAGE_HALF
#undef KG_BLOCK

  // epilogue: z[row] = sum_cols exp(logit + bo), no max (logits bounded)
  // bov loaded HERE to keep in-loop arch regs <= 64
  float bov[8];
  #pragma unroll
  for (int nt = 0; nt < 8; ++nt)
    bov[nt] = bo[v0 + nt * 16 + lr] * LOG2E;
  float z[2][4];
  #pragma unroll
  for (int mt = 0; mt < 2; ++mt)
    #pragma unroll
    for (int r = 0; r < 4; ++r) z[mt][r] = 0.f;
  #pragma unroll
  for (int mt = 0; mt < 2; ++mt)
    #pragma unroll
    for (int nt = 0; nt < 8; ++nt)
      #pragma unroll
      for (int r = 0; r < 4; ++r)
        z[mt][r] += exp2f(fmaf(acc[mt][nt][r], LOG2E, bov[nt]));
  #pragma unroll
  for (int mt = 0; mt < 2; ++mt)
    #pragma unroll
    for (int r = 0; r < 4; ++r) {
      #pragma unroll
      for (int off = 1; off < 16; off <<= 1)
        z[mt][r] += __shfl_xor(z[mt][r], off);
    }
  if (lr == 0) {
    int ch = blockIdx.y;
    #pragma unroll
    for (int mt = 0; mt < 2; ++mt) {
      float4 v4;
      v4.x = z[mt][0]; v4.y = z[mt][1]; v4.z = z[mt][2]; v4.w = z[mt][3];
      *(float4*)&pz[(size_t)ch * L + l0 + w * 32 + mt * 16 + lq * 4] = v4;
    }
  }
}

// ---------------------------------------------------------------- kernel F
// Fused tail: pz reduce + tag logit + loss + global mean. 256 blocks x 16
// labels (vs R12: reduce on 16 blocks = 6% of CUs, 250-load latency chain,
// plus a separate tag launch). Phase 1: 16-way chunk-partitioned reduce
// (~16 independent coalesced loads/thread). Phase 2: 4 tag dots per wave.
// One launch + one atomic per block. logits2/prep/feat untouched.
__global__ __launch_bounds__(256) void final_kernel(
    const ushort* __restrict__ featb, const ushort* __restrict__ Wob,
    const float* __restrict__ bo, const int* __restrict__ tags,
    const float* __restrict__ pz, float* __restrict__ out) {
  __shared__ float zp[256];
  __shared__ float zl[16];
  __shared__ float wsum[4];
  int tid = threadIdx.x;
  int lb = blockIdx.x * 16;
  int lab = tid & 15, cpart = tid >> 4;  // 16 chunk partitions x 16 labels

  // phase 1: zsum for 16 labels, 16-way chunk split
  {
    float zs = 0.f;
    for (int c = cpart; c < NCH; c += 16)
      zs += pz[(size_t)c * L + lb + lab];
    zp[tid] = zs;
  }
  __syncthreads();
  if (tid < 16) {
    float s = 0.f;
    #pragma unroll
    for (int p = 0; p < 16; ++p) s += zp[p * 16 + tid];
    zl[tid] = s;
  }
  __syncthreads();

  // phase 2: tag dots (frag-major Wob gather), 4 labels per wave
  int w = tid >> 6, lane = tid & 63;
  float psum = 0.f;
  #pragma unroll
  for (int i = 0; i < 4; ++i) {
    int li = w * 4 + i;
    int l = lb + li;
    int tg = tags[l];
    int c = tg >> 7, nt = (tg >> 4) & 7, lr = tg & 15;
    int k0 = lane << 2;
    int kh = k0 >> 7, k4 = (k0 >> 5) & 3, lq = (k0 >> 3) & 3, e = k0 & 7;
    size_t f = ((((size_t)c * 2 + kh) * 4 + k4) * 8 + nt) * 64 + lq * 16 + lr;
    ushort4 wa = *(const ushort4*)&Wob[f * 8 + e];
    ushort4 fa = *(const ushort4*)&featb[(size_t)l * 256 + k0];
    float s = bf2f(fa.x) * bf2f(wa.x) + bf2f(fa.y) * bf2f(wa.y) +
              bf2f(fa.z) * bf2f(wa.z) + bf2f(fa.w) * bf2f(wa.w);
    #pragma unroll
    for (int off = 1; off < 64; off <<= 1) s += __shfl_xor(s, off);
    if (lane == 0)
      psum += logf(zl[li]) - (s + bo[tg]);
  }
  if (lane == 0) wsum[w] = psum;
  __syncthreads();
  if (tid == 0) {
    float v = (wsum[0] + wsum[1] + wsum[2] + wsum[3]) *
              (1.0f / (4096.0f + 1e-5f));
    atomicAdd(out, v);
  }
}

// ---------------------------------------------------------------- launch
extern "C" void kernel_launch(void* const* d_in, const int* in_sizes, int n_in,
                              void* d_out, int out_size, void* d_ws,
                              size_t ws_size, hipStream_t stream) {
  const float* hidden = (const float*)d_in[0];
  const int* begins = (const int*)d_in[1];
  const int* ends = (const int*)d_in[2];
  const int* bids = (const int*)d_in[3];
  const int* tags = (const int*)d_in[4];
  const float* W1 = (const float*)d_in[5];
  const float* b1 = (const float*)d_in[6];
  const float* W2 = (const float*)d_in[7];
  const float* b2 = (const float*)d_in[8];
  const float* Wo = (const float*)d_in[9];
  const float* bo = (const float*)d_in[10];
  float* out = (float*)d_out;

  ushort* featb = (ushort*)d_ws;                       // L*256
  ushort* Wob = featb + (size_t)L * 256;               // V*256 (frag-major)
  ushort* spanb = Wob + (size_t)V * 256;               // L*1536
  ushort* W1b = spanb + (size_t)L * 1536;              // 256*1536
  ushort* W2b = W1b + (size_t)256 * 1536;              // 256*256
  // pz (NCH*L f32 = 4.1 MB) aliases spanb (12.6 MB): spanb dead after
  // feat_mfma_kernel; logits2 runs strictly after it in-stream.
  float* pz = (float*)spanb;

  prep_kernel<<<4160, 256, 0, stream>>>(hidden, begins, ends, bids, spanb,
                                        W1, W1b, W2, W2b, Wo, Wob);
  feat_mfma_kernel<<<256, 256, 0, stream>>>(spanb, W1b, b1, W2b, b2, featb,
                                            out);
  logits2_kernel<<<dim3(16, NCH), 512, 0, stream>>>(featb, Wob, bo, pz);
  final_kernel<<<256, 256, 0, stream>>>(featb, Wob, bo, tags, pz, out);
}